// Round 10
// baseline (1196.772 us; speedup 1.0000x reference)
//
#include <hip/hip_runtime.h>

#define N_NODES 100000
#define N_EDGES 1000000

typedef __attribute__((ext_vector_type(8))) short bf16x8;
typedef __attribute__((ext_vector_type(4))) float f32x4;
typedef unsigned short ushort_t;

// split fp32 v into hi+lo bf16 (truncation; lo captures residual; net err ~2^-17)
__device__ __forceinline__ void bsplit(float v, unsigned& hi, unsigned& lo) {
  unsigned u = __float_as_uint(v);
  hi = u >> 16;
  float hf = __uint_as_float(hi << 16);
  lo = __float_as_uint(v - hf) >> 16;
}

// ---------------- zero kernels ----------------
__global__ __launch_bounds__(256) void zero_kernel(float4* __restrict__ p, long n4) {
  long i = (long)blockIdx.x * 256 + threadIdx.x;
  long stride = (long)gridDim.x * 256;
  float4 z = make_float4(0.f, 0.f, 0.f, 0.f);
  for (; i < n4; i += stride) p[i] = z;
}
__global__ __launch_bounds__(256) void zero_int_kernel(int* __restrict__ p, long n) {
  long i = (long)blockIdx.x * 256 + threadIdx.x;
  long stride = (long)gridDim.x * 256;
  for (; i < n; i += stride) p[i] = 0;
}

// ---------------- encoder: h0 = relu(x @ enc_w + enc_b) -> split bf16 hi/lo ----------------
__global__ __launch_bounds__(256) void encoder_kernel(
    const float* __restrict__ x, const float* __restrict__ w,
    const float* __restrict__ b, ushort_t* __restrict__ hhi,
    ushort_t* __restrict__ hlo) {
  __shared__ float ws[32 * 128];
  __shared__ float xs[16 * 32];
  __shared__ float bs[128];
  int tid = threadIdx.x;
#pragma unroll
  for (int i = 0; i < 4; ++i)
    reinterpret_cast<float4*>(ws)[tid + i * 256] =
        reinterpret_cast<const float4*>(w)[tid + i * 256];
  if (tid < 128) bs[tid] = b[tid];
  int n0 = blockIdx.x * 16;
  if (tid < 128)
    reinterpret_cast<float4*>(xs)[tid] =
        reinterpret_cast<const float4*>(x + (size_t)n0 * 32)[tid];
  __syncthreads();
  int f = tid & 127;
  int ng = tid >> 7;
#pragma unroll
  for (int i = 0; i < 8; ++i) {
    int nl = ng * 8 + i;
    float acc = bs[f];
#pragma unroll
    for (int k = 0; k < 32; ++k) acc = fmaf(xs[nl * 32 + k], ws[k * 128 + f], acc);
    float v = fmaxf(acc, 0.f);
    unsigned h_, l_;
    bsplit(v, h_, l_);
    size_t idx = (size_t)(n0 + nl) * 128 + f;
    hhi[idx] = (ushort_t)h_;
    hlo[idx] = (ushort_t)l_;
  }
}

// ---------------- histogram / scan / fill (CSR build) ----------------
__global__ __launch_bounds__(256) void hist_kernel(const int* __restrict__ ei,
                                                   int* __restrict__ deg) {
  int e = blockIdx.x * 256 + threadIdx.x;
  if (e < N_EDGES) atomicAdd(&deg[ei[N_EDGES + e]], 1);
}

__global__ __launch_bounds__(1024) void scan_kernel(const int* __restrict__ deg,
                                                    int* __restrict__ row_start) {
  __shared__ int part[1024];
  int tid = threadIdx.x;
  const int CH = (N_NODES + 1023) / 1024;
  int start = tid * CH;
  int sum = 0;
  for (int i = 0; i < CH; ++i) {
    int idx = start + i;
    if (idx < N_NODES) sum += deg[idx];
  }
  part[tid] = sum;
  __syncthreads();
  for (int off = 1; off < 1024; off <<= 1) {
    int v = (tid >= off) ? part[tid - off] : 0;
    __syncthreads();
    part[tid] += v;
    __syncthreads();
  }
  int prefix = (tid == 0) ? 0 : part[tid - 1];
  for (int i = 0; i < CH; ++i) {
    int idx = start + i;
    if (idx < N_NODES) {
      row_start[idx] = prefix;
      prefix += deg[idx];
    }
  }
}

__global__ __launch_bounds__(256) void fill_kernel(
    const int* __restrict__ ei, const int* __restrict__ row_start,
    int* __restrict__ cursor, int* __restrict__ csr_eidx) {
  int e = blockIdx.x * 256 + threadIdx.x;
  if (e >= N_EDGES) return;
  int d = ei[N_EDGES + e];
  int pos = atomicAdd(&cursor[d], 1);
  csr_eidx[row_start[d] + pos] = e;
}

// ---------------- W transpose + split: W[K2][N] fp32 -> WT hi/lo [N][K2] bf16 ----------------
__global__ __launch_bounds__(256) void wsplit_kernel(
    const float* __restrict__ W, ushort_t* __restrict__ hi,
    ushort_t* __restrict__ lo, int K2, int N) {
  __shared__ float t[32][33];
  int bx = blockIdx.x * 32;  // n
  int by = blockIdx.y * 32;  // k
  int lx = threadIdx.x & 31, ly = threadIdx.x >> 5;  // ly 0..7
#pragma unroll
  for (int i = 0; i < 4; ++i)
    t[ly + i * 8][lx] = W[(size_t)(by + ly + i * 8) * N + bx + lx];
  __syncthreads();
#pragma unroll
  for (int i = 0; i < 4; ++i) {
    int n_l = ly + i * 8;
    float v = t[lx][n_l];  // k_local=lx, n_local=n_l
    unsigned h_, l_;
    bsplit(v, h_, l_);
    hi[(size_t)(bx + n_l) * K2 + by + lx] = (ushort_t)h_;
    lo[(size_t)(bx + n_l) * K2 + by + lx] = (ushort_t)l_;
  }
}

// ---------------- wave-per-node aggregate from split h: agg = mean(h[src]*eaw) -> split ----------------
template <int F>
__global__ __launch_bounds__(256) void aggregate_ws(
    const ushort_t* __restrict__ hhi, const ushort_t* __restrict__ hlo,
    const int* __restrict__ row_start, const int* __restrict__ deg,
    const int* __restrict__ csr_eidx, const int* __restrict__ ei,
    const float2* __restrict__ ea2, const float* __restrict__ ew,
    const float* __restrict__ eb, ushort_t* __restrict__ ahi,
    ushort_t* __restrict__ alo) {
  int wid = threadIdx.x >> 6, lane = threadIdx.x & 63;
  int n = blockIdx.x * 4 + wid;
  if (n >= N_NODES) return;
  int rs = row_start[n], dg = deg[n];
  float dinv = 1.f / fmaxf((float)dg, 1.f);
  if (F == 256) {
    int f0 = lane * 4;
    float4 w0 = *reinterpret_cast<const float4*>(&ew[f0]);
    float4 w1 = *reinterpret_cast<const float4*>(&ew[F + f0]);
    float4 bb = *reinterpret_cast<const float4*>(&eb[f0]);
    float a0 = 0.f, a1 = 0.f, a2 = 0.f, a3 = 0.f;
    int s = 0; float2 at = make_float2(0.f, 0.f);
    if (dg > 0) { int e = csr_eidx[rs]; s = ei[e]; at = ea2[e]; }
    for (int j = 0; j < dg; ++j) {
      int s2 = 0; float2 at2 = make_float2(0.f, 0.f);
      if (j + 1 < dg) { int e2 = csr_eidx[rs + j + 1]; s2 = ei[e2]; at2 = ea2[e2]; }
      uint2 uh = *reinterpret_cast<const uint2*>(&hhi[(size_t)s * F + f0]);
      uint2 ul = *reinterpret_cast<const uint2*>(&hlo[(size_t)s * F + f0]);
      float v0 = __uint_as_float(uh.x << 16) + __uint_as_float(ul.x << 16);
      float v1 = __uint_as_float(uh.x & 0xffff0000u) + __uint_as_float(ul.x & 0xffff0000u);
      float v2 = __uint_as_float(uh.y << 16) + __uint_as_float(ul.y << 16);
      float v3 = __uint_as_float(uh.y & 0xffff0000u) + __uint_as_float(ul.y & 0xffff0000u);
      a0 = fmaf(v0, fmaf(at.x, w0.x, fmaf(at.y, w1.x, bb.x)), a0);
      a1 = fmaf(v1, fmaf(at.x, w0.y, fmaf(at.y, w1.y, bb.y)), a1);
      a2 = fmaf(v2, fmaf(at.x, w0.z, fmaf(at.y, w1.z, bb.z)), a2);
      a3 = fmaf(v3, fmaf(at.x, w0.w, fmaf(at.y, w1.w, bb.w)), a3);
      s = s2; at = at2;
    }
    unsigned h_, l_;
    uint2 oh, ol;
    bsplit(a0 * dinv, h_, l_); oh.x = h_;        ol.x = l_;
    bsplit(a1 * dinv, h_, l_); oh.x |= h_ << 16; ol.x |= l_ << 16;
    bsplit(a2 * dinv, h_, l_); oh.y = h_;        ol.y = l_;
    bsplit(a3 * dinv, h_, l_); oh.y |= h_ << 16; ol.y |= l_ << 16;
    *reinterpret_cast<uint2*>(&ahi[(size_t)n * F + f0]) = oh;
    *reinterpret_cast<uint2*>(&alo[(size_t)n * F + f0]) = ol;
  } else {  // F == 128
    int f0 = lane * 2;
    float2 w0 = *reinterpret_cast<const float2*>(&ew[f0]);
    float2 w1 = *reinterpret_cast<const float2*>(&ew[F + f0]);
    float2 bb = *reinterpret_cast<const float2*>(&eb[f0]);
    float a0 = 0.f, a1 = 0.f;
    int s = 0; float2 at = make_float2(0.f, 0.f);
    if (dg > 0) { int e = csr_eidx[rs]; s = ei[e]; at = ea2[e]; }
    for (int j = 0; j < dg; ++j) {
      int s2 = 0; float2 at2 = make_float2(0.f, 0.f);
      if (j + 1 < dg) { int e2 = csr_eidx[rs + j + 1]; s2 = ei[e2]; at2 = ea2[e2]; }
      unsigned uh = *reinterpret_cast<const unsigned*>(&hhi[(size_t)s * F + f0]);
      unsigned ul = *reinterpret_cast<const unsigned*>(&hlo[(size_t)s * F + f0]);
      float v0 = __uint_as_float(uh << 16) + __uint_as_float(ul << 16);
      float v1 = __uint_as_float(uh & 0xffff0000u) + __uint_as_float(ul & 0xffff0000u);
      a0 = fmaf(v0, fmaf(at.x, w0.x, fmaf(at.y, w1.x, bb.x)), a0);
      a1 = fmaf(v1, fmaf(at.x, w0.y, fmaf(at.y, w1.y, bb.y)), a1);
      s = s2; at = at2;
    }
    unsigned h0_, l0_, h1_, l1_;
    bsplit(a0 * dinv, h0_, l0_);
    bsplit(a1 * dinv, h1_, l1_);
    *reinterpret_cast<unsigned*>(&ahi[(size_t)n * F + f0]) = h0_ | (h1_ << 16);
    *reinterpret_cast<unsigned*>(&alo[(size_t)n * F + f0]) = l0_ | (l1_ << 16);
  }
}

// ---------------- split-bf16 MFMA GEMM, pre-split inputs (pure-copy staging) ----------------
// T = relu([A1|A2] @ W + bias); !FUSE_DEC: C=T split to chi/clo; FUSE_DEC: out += T @ dw (+db once)
// BM=128, BN=256, BK=32, 512 thr = 8 waves (wm2 x wn4), wave tile 64x64 = acc[4][4] 16x16.
template <bool FUSE_DEC>
__global__ __launch_bounds__(512) void gemm2_mfma(
    const ushort_t* __restrict__ a1hi, const ushort_t* __restrict__ a1lo,
    const ushort_t* __restrict__ a2hi, const ushort_t* __restrict__ a2lo,
    const ushort_t* __restrict__ wthi, const ushort_t* __restrict__ wtlo,
    const float* __restrict__ bias, ushort_t* __restrict__ chi,
    ushort_t* __restrict__ clo, const float* __restrict__ dw,
    const float* __restrict__ db, float* __restrict__ out, int M, int F, int N) {
  constexpr int LDK = 40;  // 32 + 8 pad shorts; 80B rows, 16B-aligned granules
  __shared__ alignas(16) ushort_t Ah[128 * LDK];
  __shared__ alignas(16) ushort_t Al[128 * LDK];
  __shared__ alignas(16) ushort_t Bh[256 * LDK];
  __shared__ alignas(16) ushort_t Bl[256 * LDK];
  int tid = threadIdx.x;
  int wid = tid >> 6, lane = tid & 63;
  int wm = wid >> 2, wn = wid & 3;
  int lg = lane >> 4, lr = lane & 15;
  int row0 = blockIdx.y * 128;
  int col0 = blockIdx.x * 256;
  int K2 = 2 * F;
  f32x4 acc[4][4] = {};
  int ar = tid >> 2, ag = tid & 3;  // A-stage: 128 rows x 4 granules

  for (int pass = 0; pass < 2; ++pass) {
    const ushort_t* Ahg = pass ? a2hi : a1hi;
    const ushort_t* Alg = pass ? a2lo : a1lo;
    for (int k0 = 0; k0 < F; k0 += 32) {
      __syncthreads();  // previous frags consumed
      {  // A stage: pure b128 copy
        int gr = row0 + ar;
        bf16x8 vh = {}, vl = {};
        if (gr < M) {
          vh = *reinterpret_cast<const bf16x8*>(&Ahg[(size_t)gr * F + k0 + ag * 8]);
          vl = *reinterpret_cast<const bf16x8*>(&Alg[(size_t)gr * F + k0 + ag * 8]);
        }
        *reinterpret_cast<bf16x8*>(&Ah[ar * LDK + ag * 8]) = vh;
        *reinterpret_cast<bf16x8*>(&Al[ar * LDK + ag * 8]) = vl;
      }
      int kk = pass * F + k0;
#pragma unroll
      for (int i = 0; i < 2; ++i) {  // B stage: 256 cols x 4 granules
        int id = tid + i * 512;
        int c = id >> 2, g = id & 3;
        *reinterpret_cast<bf16x8*>(&Bh[c * LDK + g * 8]) =
            *reinterpret_cast<const bf16x8*>(&wthi[(size_t)(col0 + c) * K2 + kk + g * 8]);
        *reinterpret_cast<bf16x8*>(&Bl[c * LDK + g * 8]) =
            *reinterpret_cast<const bf16x8*>(&wtlo[(size_t)(col0 + c) * K2 + kk + g * 8]);
      }
      __syncthreads();
      bf16x8 fah[4], fal[4];
#pragma unroll
      for (int m = 0; m < 4; ++m) {
        int rr = wm * 64 + m * 16 + lr;
        fah[m] = *reinterpret_cast<const bf16x8*>(&Ah[rr * LDK + lg * 8]);
        fal[m] = *reinterpret_cast<const bf16x8*>(&Al[rr * LDK + lg * 8]);
      }
#pragma unroll
      for (int nn = 0; nn < 4; ++nn) {
        int cc = wn * 64 + nn * 16 + lr;
        bf16x8 fbh = *reinterpret_cast<const bf16x8*>(&Bh[cc * LDK + lg * 8]);
        bf16x8 fbl = *reinterpret_cast<const bf16x8*>(&Bl[cc * LDK + lg * 8]);
#pragma unroll
        for (int m = 0; m < 4; ++m) {
          acc[m][nn] = __builtin_amdgcn_mfma_f32_16x16x32_bf16(fah[m], fbh, acc[m][nn], 0, 0, 0);
          acc[m][nn] = __builtin_amdgcn_mfma_f32_16x16x32_bf16(fah[m], fbl, acc[m][nn], 0, 0, 0);
          acc[m][nn] = __builtin_amdgcn_mfma_f32_16x16x32_bf16(fal[m], fbh, acc[m][nn], 0, 0, 0);
        }
      }
    }
  }
  // epilogue: D layout col = lr, row = lg*4 + r
  if (!FUSE_DEC) {
#pragma unroll
    for (int m = 0; m < 4; ++m) {
#pragma unroll
      for (int r = 0; r < 4; ++r) {
        int grow = row0 + wm * 64 + m * 16 + lg * 4 + r;
        if (grow >= M) continue;
#pragma unroll
        for (int nn = 0; nn < 4; ++nn) {
          int gcol = col0 + wn * 64 + nn * 16 + lr;
          float v = fmaxf(acc[m][nn][r] + bias[gcol], 0.f);
          unsigned h_, l_;
          bsplit(v, h_, l_);
          chi[(size_t)grow * N + gcol] = (ushort_t)h_;
          clo[(size_t)grow * N + gcol] = (ushort_t)l_;
        }
      }
    }
  } else {
#pragma unroll
    for (int m = 0; m < 4; ++m) {
#pragma unroll
      for (int r = 0; r < 4; ++r) {
        int grow = row0 + wm * 64 + m * 16 + lg * 4 + r;
        float p0 = 0.f, p1 = 0.f;
        if (grow < M) {
#pragma unroll
          for (int nn = 0; nn < 4; ++nn) {
            int gcol = col0 + wn * 64 + nn * 16 + lr;
            float v = fmaxf(acc[m][nn][r] + bias[gcol], 0.f);
            p0 = fmaf(v, dw[gcol * 2 + 0], p0);
            p1 = fmaf(v, dw[gcol * 2 + 1], p1);
          }
        }
#pragma unroll
        for (int s = 1; s < 16; s <<= 1) {  // reduce over lr (same row across 16 lanes)
          p0 += __shfl_xor(p0, s);
          p1 += __shfl_xor(p1, s);
        }
        if (lr == 0 && grow < M) {
          if (wn == 0 && blockIdx.x == 0) { p0 += db[0]; p1 += db[1]; }
          atomicAdd(&out[(size_t)grow * 2 + 0], p0);
          atomicAdd(&out[(size_t)grow * 2 + 1], p1);
        }
      }
    }
  }
}

extern "C" void kernel_launch(void* const* d_in, const int* in_sizes, int n_in,
                              void* d_out, int out_size, void* d_ws, size_t ws_size,
                              hipStream_t stream) {
  const float* x        = (const float*)d_in[0];
  const float* edge_attr= (const float*)d_in[1];
  const int*   ei       = (const int*)d_in[2];
  const float* enc_w    = (const float*)d_in[3];
  const float* enc_b    = (const float*)d_in[4];
  const float* e_w0     = (const float*)d_in[5];
  const float* e_b0     = (const float*)d_in[6];
  const float* l_w0     = (const float*)d_in[7];
  const float* l_b0     = (const float*)d_in[8];
  const float* e_w1     = (const float*)d_in[9];
  const float* e_b1     = (const float*)d_in[10];
  const float* l_w1     = (const float*)d_in[11];
  const float* l_b1     = (const float*)d_in[12];
  const float* dec_w    = (const float*)d_in[13];
  const float* dec_b    = (const float*)d_in[14];
  float* out = (float*)d_out;

  // Workspace (211 MB), all carve-outs 16B-aligned:
  //  [h0hi 25.6|h0lo 25.6|agg0hi 25.6|agg0lo 25.6|h1hi 51.2|h1lo 51.2|WT 1.3|deg/row/eidx 4.8]
  //  agg1hi/lo alias [h0*, agg0*] (dead after gemm0); cursor aliases agg0hi (dead until agg<128>).
  char* base = (char*)d_ws;
  ushort_t* h0hi   = (ushort_t*)(base);
  ushort_t* h0lo   = (ushort_t*)(base + 25600000);
  ushort_t* agg0hi = (ushort_t*)(base + 51200000);
  ushort_t* agg0lo = (ushort_t*)(base + 76800000);
  ushort_t* h1hi   = (ushort_t*)(base + 102400000);
  ushort_t* h1lo   = (ushort_t*)(base + 153600000);
  ushort_t* wt0hi  = (ushort_t*)(base + 204800000);
  ushort_t* wt0lo  = wt0hi + 256 * 256;
  ushort_t* wt1hi  = wt0lo + 256 * 256;
  ushort_t* wt1lo  = wt1hi + 512 * 512;
  int* deg_i    = (int*)(base + 206200000);
  int* row_s    = deg_i + N_NODES;
  int* csr_eidx = row_s + N_NODES;
  int* cursor   = (int*)agg0hi;
  ushort_t* agg1hi = (ushort_t*)(base);
  ushort_t* agg1lo = (ushort_t*)(base + 51200000);
  const float2* ea2 = (const float2*)edge_attr;

  const int M = N_NODES;
  const int ZB = 1024;

  zero_int_kernel<<<ZB, 256, 0, stream>>>(deg_i, N_NODES);
  zero_int_kernel<<<ZB, 256, 0, stream>>>(cursor, N_NODES);

  encoder_kernel<<<N_NODES / 16, 256, 0, stream>>>(x, enc_w, enc_b, h0hi, h0lo);
  hist_kernel<<<(N_EDGES + 255) / 256, 256, 0, stream>>>(ei, deg_i);
  scan_kernel<<<1, 1024, 0, stream>>>(deg_i, row_s);
  fill_kernel<<<(N_EDGES + 255) / 256, 256, 0, stream>>>(ei, row_s, cursor, csr_eidx);

  wsplit_kernel<<<dim3(8, 8), 256, 0, stream>>>(l_w0, wt0hi, wt0lo, 256, 256);
  wsplit_kernel<<<dim3(16, 16), 256, 0, stream>>>(l_w1, wt1hi, wt1lo, 512, 512);

  // conv0
  aggregate_ws<128><<<N_NODES / 4, 256, 0, stream>>>(h0hi, h0lo, row_s, deg_i, csr_eidx,
                                                     ei, ea2, e_w0, e_b0, agg0hi, agg0lo);
  gemm2_mfma<false><<<dim3(1, (M + 127) / 128), 512, 0, stream>>>(
      agg0hi, agg0lo, h0hi, h0lo, wt0hi, wt0lo, l_b0, h1hi, h1lo,
      nullptr, nullptr, nullptr, M, 128, 256);

  // conv1 (agg1 overwrites h0/agg0 region — dead after gemm0)
  aggregate_ws<256><<<N_NODES / 4, 256, 0, stream>>>(h1hi, h1lo, row_s, deg_i, csr_eidx,
                                                     ei, ea2, e_w1, e_b1, agg1hi, agg1lo);

  zero_kernel<<<ZB, 256, 0, stream>>>((float4*)out, (long)out_size / 4);
  gemm2_mfma<true><<<dim3(2, (M + 127) / 128), 512, 0, stream>>>(
      agg1hi, agg1lo, h1hi, h1lo, wt1hi, wt1lo, l_b1, nullptr, nullptr,
      dec_w, dec_b, out, M, 256, 512);
}

// Round 15
// 1176.848 us; speedup vs baseline: 1.0169x; 1.0169x over previous
//
#include <hip/hip_runtime.h>

#define N_NODES 100000
#define N_EDGES 1000000

typedef __attribute__((ext_vector_type(8))) short bf16x8;
typedef __attribute__((ext_vector_type(4))) float f32x4;
typedef unsigned short ushort_t;

// split fp32 v into hi+lo bf16 (truncation; lo captures residual; net err ~2^-17)
__device__ __forceinline__ void bsplit(float v, unsigned& hi, unsigned& lo) {
  unsigned u = __float_as_uint(v);
  hi = u >> 16;
  float hf = __uint_as_float(hi << 16);
  lo = __float_as_uint(v - hf) >> 16;
}

// ---------------- zero kernels ----------------
__global__ __launch_bounds__(256) void zero_kernel(float4* __restrict__ p, long n4) {
  long i = (long)blockIdx.x * 256 + threadIdx.x;
  long stride = (long)gridDim.x * 256;
  float4 z = make_float4(0.f, 0.f, 0.f, 0.f);
  for (; i < n4; i += stride) p[i] = z;
}
__global__ __launch_bounds__(256) void zero_int_kernel(int* __restrict__ p, long n) {
  long i = (long)blockIdx.x * 256 + threadIdx.x;
  long stride = (long)gridDim.x * 256;
  for (; i < n; i += stride) p[i] = 0;
}

// ---------------- encoder: h0 = relu(x @ enc_w + enc_b) -> split bf16 hi/lo ----------------
__global__ __launch_bounds__(256) void encoder_kernel(
    const float* __restrict__ x, const float* __restrict__ w,
    const float* __restrict__ b, ushort_t* __restrict__ hhi,
    ushort_t* __restrict__ hlo) {
  __shared__ float ws[32 * 128];
  __shared__ float xs[16 * 32];
  __shared__ float bs[128];
  int tid = threadIdx.x;
#pragma unroll
  for (int i = 0; i < 4; ++i)
    reinterpret_cast<float4*>(ws)[tid + i * 256] =
        reinterpret_cast<const float4*>(w)[tid + i * 256];
  if (tid < 128) bs[tid] = b[tid];
  int n0 = blockIdx.x * 16;
  if (tid < 128)
    reinterpret_cast<float4*>(xs)[tid] =
        reinterpret_cast<const float4*>(x + (size_t)n0 * 32)[tid];
  __syncthreads();
  int f = tid & 127;
  int ng = tid >> 7;
#pragma unroll
  for (int i = 0; i < 8; ++i) {
    int nl = ng * 8 + i;
    float acc = bs[f];
#pragma unroll
    for (int k = 0; k < 32; ++k) acc = fmaf(xs[nl * 32 + k], ws[k * 128 + f], acc);
    float v = fmaxf(acc, 0.f);
    unsigned h_, l_;
    bsplit(v, h_, l_);
    size_t idx = (size_t)(n0 + nl) * 128 + f;
    hhi[idx] = (ushort_t)h_;
    hlo[idx] = (ushort_t)l_;
  }
}

// ---------------- histogram / scan / fill (CSR build) ----------------
__global__ __launch_bounds__(256) void hist_kernel(const int* __restrict__ ei,
                                                   int* __restrict__ deg) {
  int e = blockIdx.x * 256 + threadIdx.x;
  if (e < N_EDGES) atomicAdd(&deg[ei[N_EDGES + e]], 1);
}

__global__ __launch_bounds__(1024) void scan_kernel(const int* __restrict__ deg,
                                                    int* __restrict__ row_start) {
  __shared__ int part[1024];
  int tid = threadIdx.x;
  const int CH = (N_NODES + 1023) / 1024;
  int start = tid * CH;
  int sum = 0;
  for (int i = 0; i < CH; ++i) {
    int idx = start + i;
    if (idx < N_NODES) sum += deg[idx];
  }
  part[tid] = sum;
  __syncthreads();
  for (int off = 1; off < 1024; off <<= 1) {
    int v = (tid >= off) ? part[tid - off] : 0;
    __syncthreads();
    part[tid] += v;
    __syncthreads();
  }
  int prefix = (tid == 0) ? 0 : part[tid - 1];
  for (int i = 0; i < CH; ++i) {
    int idx = start + i;
    if (idx < N_NODES) {
      row_start[idx] = prefix;
      prefix += deg[idx];
    }
  }
}

__global__ __launch_bounds__(256) void fill_kernel(
    const int* __restrict__ ei, const int* __restrict__ row_start,
    int* __restrict__ cursor, int* __restrict__ csr_eidx) {
  int e = blockIdx.x * 256 + threadIdx.x;
  if (e >= N_EDGES) return;
  int d = ei[N_EDGES + e];
  int pos = atomicAdd(&cursor[d], 1);
  csr_eidx[row_start[d] + pos] = e;
}

// ---------------- W transpose + split: W[K2][N] fp32 -> WT hi/lo [N][K2] bf16 ----------------
__global__ __launch_bounds__(256) void wsplit_kernel(
    const float* __restrict__ W, ushort_t* __restrict__ hi,
    ushort_t* __restrict__ lo, int K2, int N) {
  __shared__ float t[32][33];
  int bx = blockIdx.x * 32;  // n
  int by = blockIdx.y * 32;  // k
  int lx = threadIdx.x & 31, ly = threadIdx.x >> 5;  // ly 0..7
#pragma unroll
  for (int i = 0; i < 4; ++i)
    t[ly + i * 8][lx] = W[(size_t)(by + ly + i * 8) * N + bx + lx];
  __syncthreads();
#pragma unroll
  for (int i = 0; i < 4; ++i) {
    int n_l = ly + i * 8;
    float v = t[lx][n_l];  // k_local=lx, n_local=n_l
    unsigned h_, l_;
    bsplit(v, h_, l_);
    hi[(size_t)(bx + n_l) * K2 + by + lx] = (ushort_t)h_;
    lo[(size_t)(bx + n_l) * K2 + by + lx] = (ushort_t)l_;
  }
}

// ---------------- wave-per-node aggregate from split h: agg = mean(h[src]*eaw) -> split ----------------
template <int F>
__global__ __launch_bounds__(256) void aggregate_ws(
    const ushort_t* __restrict__ hhi, const ushort_t* __restrict__ hlo,
    const int* __restrict__ row_start, const int* __restrict__ deg,
    const int* __restrict__ csr_eidx, const int* __restrict__ ei,
    const float2* __restrict__ ea2, const float* __restrict__ ew,
    const float* __restrict__ eb, ushort_t* __restrict__ ahi,
    ushort_t* __restrict__ alo) {
  int wid = threadIdx.x >> 6, lane = threadIdx.x & 63;
  int n = blockIdx.x * 4 + wid;
  if (n >= N_NODES) return;
  int rs = row_start[n], dg = deg[n];
  float dinv = 1.f / fmaxf((float)dg, 1.f);
  if (F == 256) {
    int f0 = lane * 4;
    float4 w0 = *reinterpret_cast<const float4*>(&ew[f0]);
    float4 w1 = *reinterpret_cast<const float4*>(&ew[F + f0]);
    float4 bb = *reinterpret_cast<const float4*>(&eb[f0]);
    float a0 = 0.f, a1 = 0.f, a2 = 0.f, a3 = 0.f;
    int s = 0; float2 at = make_float2(0.f, 0.f);
    if (dg > 0) { int e = csr_eidx[rs]; s = ei[e]; at = ea2[e]; }
    for (int j = 0; j < dg; ++j) {
      int s2 = 0; float2 at2 = make_float2(0.f, 0.f);
      if (j + 1 < dg) { int e2 = csr_eidx[rs + j + 1]; s2 = ei[e2]; at2 = ea2[e2]; }
      uint2 uh = *reinterpret_cast<const uint2*>(&hhi[(size_t)s * F + f0]);
      uint2 ul = *reinterpret_cast<const uint2*>(&hlo[(size_t)s * F + f0]);
      float v0 = __uint_as_float(uh.x << 16) + __uint_as_float(ul.x << 16);
      float v1 = __uint_as_float(uh.x & 0xffff0000u) + __uint_as_float(ul.x & 0xffff0000u);
      float v2 = __uint_as_float(uh.y << 16) + __uint_as_float(ul.y << 16);
      float v3 = __uint_as_float(uh.y & 0xffff0000u) + __uint_as_float(ul.y & 0xffff0000u);
      a0 = fmaf(v0, fmaf(at.x, w0.x, fmaf(at.y, w1.x, bb.x)), a0);
      a1 = fmaf(v1, fmaf(at.x, w0.y, fmaf(at.y, w1.y, bb.y)), a1);
      a2 = fmaf(v2, fmaf(at.x, w0.z, fmaf(at.y, w1.z, bb.z)), a2);
      a3 = fmaf(v3, fmaf(at.x, w0.w, fmaf(at.y, w1.w, bb.w)), a3);
      s = s2; at = at2;
    }
    unsigned h_, l_;
    uint2 oh, ol;
    bsplit(a0 * dinv, h_, l_); oh.x = h_;        ol.x = l_;
    bsplit(a1 * dinv, h_, l_); oh.x |= h_ << 16; ol.x |= l_ << 16;
    bsplit(a2 * dinv, h_, l_); oh.y = h_;        ol.y = l_;
    bsplit(a3 * dinv, h_, l_); oh.y |= h_ << 16; ol.y |= l_ << 16;
    *reinterpret_cast<uint2*>(&ahi[(size_t)n * F + f0]) = oh;
    *reinterpret_cast<uint2*>(&alo[(size_t)n * F + f0]) = ol;
  } else {  // F == 128
    int f0 = lane * 2;
    float2 w0 = *reinterpret_cast<const float2*>(&ew[f0]);
    float2 w1 = *reinterpret_cast<const float2*>(&ew[F + f0]);
    float2 bb = *reinterpret_cast<const float2*>(&eb[f0]);
    float a0 = 0.f, a1 = 0.f;
    int s = 0; float2 at = make_float2(0.f, 0.f);
    if (dg > 0) { int e = csr_eidx[rs]; s = ei[e]; at = ea2[e]; }
    for (int j = 0; j < dg; ++j) {
      int s2 = 0; float2 at2 = make_float2(0.f, 0.f);
      if (j + 1 < dg) { int e2 = csr_eidx[rs + j + 1]; s2 = ei[e2]; at2 = ea2[e2]; }
      unsigned uh = *reinterpret_cast<const unsigned*>(&hhi[(size_t)s * F + f0]);
      unsigned ul = *reinterpret_cast<const unsigned*>(&hlo[(size_t)s * F + f0]);
      float v0 = __uint_as_float(uh << 16) + __uint_as_float(ul << 16);
      float v1 = __uint_as_float(uh & 0xffff0000u) + __uint_as_float(ul & 0xffff0000u);
      a0 = fmaf(v0, fmaf(at.x, w0.x, fmaf(at.y, w1.x, bb.x)), a0);
      a1 = fmaf(v1, fmaf(at.x, w0.y, fmaf(at.y, w1.y, bb.y)), a1);
      s = s2; at = at2;
    }
    unsigned h0_, l0_, h1_, l1_;
    bsplit(a0 * dinv, h0_, l0_);
    bsplit(a1 * dinv, h1_, l1_);
    *reinterpret_cast<unsigned*>(&ahi[(size_t)n * F + f0]) = h0_ | (h1_ << 16);
    *reinterpret_cast<unsigned*>(&alo[(size_t)n * F + f0]) = l0_ | (l1_ << 16);
  }
}

// ---------------- split-bf16 MFMA GEMM, pre-split inputs, XOR-swizzled LDS (T2) ----------------
// T = relu([A1|A2] @ W + bias); !FUSE_DEC: C=T split to chi/clo; FUSE_DEC: out += T @ dw (+db once)
// BM=128, BN=256, BK=32, 512 thr = 8 waves (wm2 x wn4), wave tile 64x64 = acc[4][4] 16x16.
// LDS rows = 32 shorts (64B) = 4 16B-granules. Granule index g is XOR-swizzled with
// ((row>>1)&3) — bijective within the row (g^s stays in 0..3), and fragment reads
// (16 lanes, rows r..r+15, fixed g) hit all 32 banks 2-way = free (m136).
// NOTE round-11 bug: (row&7) mask overflows the 4-granule row -> cross-row collisions.
template <bool FUSE_DEC>
__global__ __launch_bounds__(512) void gemm2_mfma(
    const ushort_t* __restrict__ a1hi, const ushort_t* __restrict__ a1lo,
    const ushort_t* __restrict__ a2hi, const ushort_t* __restrict__ a2lo,
    const ushort_t* __restrict__ wthi, const ushort_t* __restrict__ wtlo,
    const float* __restrict__ bias, ushort_t* __restrict__ chi,
    ushort_t* __restrict__ clo, const float* __restrict__ dw,
    const float* __restrict__ db, float* __restrict__ out, int M, int F, int N) {
  __shared__ alignas(16) ushort_t Ah[128 * 32];
  __shared__ alignas(16) ushort_t Al[128 * 32];
  __shared__ alignas(16) ushort_t Bh[256 * 32];
  __shared__ alignas(16) ushort_t Bl[256 * 32];
  int tid = threadIdx.x;
  int wid = tid >> 6, lane = tid & 63;
  int wm = wid >> 2, wn = wid & 3;
  int lg = lane >> 4, lr = lane & 15;
  int row0 = blockIdx.y * 128;
  int col0 = blockIdx.x * 256;
  int K2 = 2 * F;
  f32x4 acc[4][4] = {};
  int ar = tid >> 2, ag = tid & 3;  // A-stage: 128 rows x 4 granules

  for (int pass = 0; pass < 2; ++pass) {
    const ushort_t* Ahg = pass ? a2hi : a1hi;
    const ushort_t* Alg = pass ? a2lo : a1lo;
    for (int k0 = 0; k0 < F; k0 += 32) {
      __syncthreads();  // previous frags consumed
      {  // A stage: pure b128 copy, swizzled dest
        int gr = row0 + ar;
        bf16x8 vh = {}, vl = {};
        if (gr < M) {
          vh = *reinterpret_cast<const bf16x8*>(&Ahg[(size_t)gr * F + k0 + ag * 8]);
          vl = *reinterpret_cast<const bf16x8*>(&Alg[(size_t)gr * F + k0 + ag * 8]);
        }
        int off = ar * 32 + ((ag ^ ((ar >> 1) & 3)) << 3);
        *reinterpret_cast<bf16x8*>(&Ah[off]) = vh;
        *reinterpret_cast<bf16x8*>(&Al[off]) = vl;
      }
      int kk = pass * F + k0;
#pragma unroll
      for (int i = 0; i < 2; ++i) {  // B stage: 256 cols x 4 granules, swizzled dest
        int id = tid + i * 512;
        int c = id >> 2, g = id & 3;
        int off = c * 32 + ((g ^ ((c >> 1) & 3)) << 3);
        *reinterpret_cast<bf16x8*>(&Bh[off]) =
            *reinterpret_cast<const bf16x8*>(&wthi[(size_t)(col0 + c) * K2 + kk + g * 8]);
        *reinterpret_cast<bf16x8*>(&Bl[off]) =
            *reinterpret_cast<const bf16x8*>(&wtlo[(size_t)(col0 + c) * K2 + kk + g * 8]);
      }
      __syncthreads();
      bf16x8 fah[4], fal[4];
#pragma unroll
      for (int m = 0; m < 4; ++m) {
        int rr = wm * 64 + m * 16 + lr;
        int off = rr * 32 + ((lg ^ ((rr >> 1) & 3)) << 3);
        fah[m] = *reinterpret_cast<const bf16x8*>(&Ah[off]);
        fal[m] = *reinterpret_cast<const bf16x8*>(&Al[off]);
      }
#pragma unroll
      for (int nn = 0; nn < 4; ++nn) {
        int cc = wn * 64 + nn * 16 + lr;
        int off = cc * 32 + ((lg ^ ((cc >> 1) & 3)) << 3);
        bf16x8 fbh = *reinterpret_cast<const bf16x8*>(&Bh[off]);
        bf16x8 fbl = *reinterpret_cast<const bf16x8*>(&Bl[off]);
#pragma unroll
        for (int m = 0; m < 4; ++m) {
          acc[m][nn] = __builtin_amdgcn_mfma_f32_16x16x32_bf16(fah[m], fbh, acc[m][nn], 0, 0, 0);
          acc[m][nn] = __builtin_amdgcn_mfma_f32_16x16x32_bf16(fah[m], fbl, acc[m][nn], 0, 0, 0);
          acc[m][nn] = __builtin_amdgcn_mfma_f32_16x16x32_bf16(fal[m], fbh, acc[m][nn], 0, 0, 0);
        }
      }
    }
  }
  // epilogue: D layout col = lr, row = lg*4 + r
  if (!FUSE_DEC) {
#pragma unroll
    for (int m = 0; m < 4; ++m) {
#pragma unroll
      for (int r = 0; r < 4; ++r) {
        int grow = row0 + wm * 64 + m * 16 + lg * 4 + r;
        if (grow >= M) continue;
#pragma unroll
        for (int nn = 0; nn < 4; ++nn) {
          int gcol = col0 + wn * 64 + nn * 16 + lr;
          float v = fmaxf(acc[m][nn][r] + bias[gcol], 0.f);
          unsigned h_, l_;
          bsplit(v, h_, l_);
          chi[(size_t)grow * N + gcol] = (ushort_t)h_;
          clo[(size_t)grow * N + gcol] = (ushort_t)l_;
        }
      }
    }
  } else {
#pragma unroll
    for (int m = 0; m < 4; ++m) {
#pragma unroll
      for (int r = 0; r < 4; ++r) {
        int grow = row0 + wm * 64 + m * 16 + lg * 4 + r;
        float p0 = 0.f, p1 = 0.f;
        if (grow < M) {
#pragma unroll
          for (int nn = 0; nn < 4; ++nn) {
            int gcol = col0 + wn * 64 + nn * 16 + lr;
            float v = fmaxf(acc[m][nn][r] + bias[gcol], 0.f);
            p0 = fmaf(v, dw[gcol * 2 + 0], p0);
            p1 = fmaf(v, dw[gcol * 2 + 1], p1);
          }
        }
#pragma unroll
        for (int s = 1; s < 16; s <<= 1) {  // reduce over lr (same row across 16 lanes)
          p0 += __shfl_xor(p0, s);
          p1 += __shfl_xor(p1, s);
        }
        if (lr == 0 && grow < M) {
          if (wn == 0 && blockIdx.x == 0) { p0 += db[0]; p1 += db[1]; }
          atomicAdd(&out[(size_t)grow * 2 + 0], p0);
          atomicAdd(&out[(size_t)grow * 2 + 1], p1);
        }
      }
    }
  }
}

extern "C" void kernel_launch(void* const* d_in, const int* in_sizes, int n_in,
                              void* d_out, int out_size, void* d_ws, size_t ws_size,
                              hipStream_t stream) {
  const float* x        = (const float*)d_in[0];
  const float* edge_attr= (const float*)d_in[1];
  const int*   ei       = (const int*)d_in[2];
  const float* enc_w    = (const float*)d_in[3];
  const float* enc_b    = (const float*)d_in[4];
  const float* e_w0     = (const float*)d_in[5];
  const float* e_b0     = (const float*)d_in[6];
  const float* l_w0     = (const float*)d_in[7];
  const float* l_b0     = (const float*)d_in[8];
  const float* e_w1     = (const float*)d_in[9];
  const float* e_b1     = (const float*)d_in[10];
  const float* l_w1     = (const float*)d_in[11];
  const float* l_b1     = (const float*)d_in[12];
  const float* dec_w    = (const float*)d_in[13];
  const float* dec_b    = (const float*)d_in[14];
  float* out = (float*)d_out;

  // Workspace (211 MB), all carve-outs 16B-aligned:
  //  [h0hi 25.6|h0lo 25.6|agg0hi 25.6|agg0lo 25.6|h1hi 51.2|h1lo 51.2|WT 1.3|deg/row/eidx 4.8]
  //  agg1hi/lo alias [h0*, agg0*] (dead after gemm0); cursor aliases agg0hi (dead until agg<128>).
  char* base = (char*)d_ws;
  ushort_t* h0hi   = (ushort_t*)(base);
  ushort_t* h0lo   = (ushort_t*)(base + 25600000);
  ushort_t* agg0hi = (ushort_t*)(base + 51200000);
  ushort_t* agg0lo = (ushort_t*)(base + 76800000);
  ushort_t* h1hi   = (ushort_t*)(base + 102400000);
  ushort_t* h1lo   = (ushort_t*)(base + 153600000);
  ushort_t* wt0hi  = (ushort_t*)(base + 204800000);
  ushort_t* wt0lo  = wt0hi + 256 * 256;
  ushort_t* wt1hi  = wt0lo + 256 * 256;
  ushort_t* wt1lo  = wt1hi + 512 * 512;
  int* deg_i    = (int*)(base + 206200000);
  int* row_s    = deg_i + N_NODES;
  int* csr_eidx = row_s + N_NODES;
  int* cursor   = (int*)agg0hi;
  ushort_t* agg1hi = (ushort_t*)(base);
  ushort_t* agg1lo = (ushort_t*)(base + 51200000);
  const float2* ea2 = (const float2*)edge_attr;

  const int M = N_NODES;
  const int ZB = 1024;

  zero_int_kernel<<<ZB, 256, 0, stream>>>(deg_i, N_NODES);
  zero_int_kernel<<<ZB, 256, 0, stream>>>(cursor, N_NODES);

  encoder_kernel<<<N_NODES / 16, 256, 0, stream>>>(x, enc_w, enc_b, h0hi, h0lo);
  hist_kernel<<<(N_EDGES + 255) / 256, 256, 0, stream>>>(ei, deg_i);
  scan_kernel<<<1, 1024, 0, stream>>>(deg_i, row_s);
  fill_kernel<<<(N_EDGES + 255) / 256, 256, 0, stream>>>(ei, row_s, cursor, csr_eidx);

  wsplit_kernel<<<dim3(8, 8), 256, 0, stream>>>(l_w0, wt0hi, wt0lo, 256, 256);
  wsplit_kernel<<<dim3(16, 16), 256, 0, stream>>>(l_w1, wt1hi, wt1lo, 512, 512);

  // conv0
  aggregate_ws<128><<<N_NODES / 4, 256, 0, stream>>>(h0hi, h0lo, row_s, deg_i, csr_eidx,
                                                     ei, ea2, e_w0, e_b0, agg0hi, agg0lo);
  gemm2_mfma<false><<<dim3(1, (M + 127) / 128), 512, 0, stream>>>(
      agg0hi, agg0lo, h0hi, h0lo, wt0hi, wt0lo, l_b0, h1hi, h1lo,
      nullptr, nullptr, nullptr, M, 128, 256);

  // conv1 (agg1 overwrites h0/agg0 region — dead after gemm0)
  aggregate_ws<256><<<N_NODES / 4, 256, 0, stream>>>(h1hi, h1lo, row_s, deg_i, csr_eidx,
                                                     ei, ea2, e_w1, e_b1, agg1hi, agg1lo);

  zero_kernel<<<ZB, 256, 0, stream>>>((float4*)out, (long)out_size / 4);
  gemm2_mfma<true><<<dim3(2, (M + 127) / 128), 512, 0, stream>>>(
      agg1hi, agg1lo, h1hi, h1lo, wt1hi, wt1lo, l_b1, nullptr, nullptr,
      dec_w, dec_b, out, M, 256, 512);
}